// Round 2
// baseline (147.210 us; speedup 1.0000x reference)
//
#include <hip/hip_runtime.h>
#include <math.h>

#define N_ROWS 4096
#define DIM 256
constexpr float INV_T = 10.0f;

#define NT 32                   // 4096 / 128 tiles per view side
#define NTILES 528              // NT*(NT+1)/2 upper-triangular tiles
#define TOTAL_BLOCKS (2 * NTILES)
#define BM 128
#define BK 64

typedef __attribute__((ext_vector_type(8))) short short8;   // bf16x8 MFMA operand
typedef __attribute__((ext_vector_type(4))) float floatx4;  // fp32x4 accumulator

typedef __attribute__((address_space(3))) unsigned int lds_uint;
typedef const __attribute__((address_space(1))) unsigned int glb_uint;

__device__ __forceinline__ unsigned short f2bf(float f) {
    unsigned int u = __float_as_uint(f);
    return (unsigned short)((u + 0x7FFFu + ((u >> 16) & 1u)) >> 16);  // RNE
}

// Kernel 1: one wave per row. L2-normalized bf16 rows of z_j -> R0, z_i -> R1,
// pos[r] = dot(zi_n, zj_n)*10. Also zeroes denom[8192] + completion counter.
__global__ __launch_bounds__(256) void normalize_kernel(
    const float* __restrict__ z_i, const float* __restrict__ z_j,
    unsigned short* __restrict__ R0, unsigned short* __restrict__ R1,
    float* __restrict__ pos, unsigned int* __restrict__ zero_region)
{
    int gid = blockIdx.x * 256 + threadIdx.x;
    if (gid < 2 * N_ROWS + 1) zero_region[gid] = 0u;   // denom + counter

    int wave = threadIdx.x >> 6;
    int lane = threadIdx.x & 63;
    int row = blockIdx.x * 4 + wave;

    float4 a = ((const float4*)(z_i + (size_t)row * DIM))[lane];
    float4 b = ((const float4*)(z_j + (size_t)row * DIM))[lane];

    float ssa = a.x*a.x + a.y*a.y + a.z*a.z + a.w*a.w;
    float ssb = b.x*b.x + b.y*b.y + b.z*b.z + b.w*b.w;
    float dab = a.x*b.x + a.y*b.y + a.z*b.z + a.w*b.w;
    #pragma unroll
    for (int off = 1; off < 64; off <<= 1) {
        ssa += __shfl_xor(ssa, off);
        ssb += __shfl_xor(ssb, off);
        dab += __shfl_xor(dab, off);
    }
    float ra = rsqrtf(ssa);
    float rb = rsqrtf(ssb);

    ushort4 ua, ub;
    ua.x = f2bf(a.x * ra); ua.y = f2bf(a.y * ra); ua.z = f2bf(a.z * ra); ua.w = f2bf(a.w * ra);
    ub.x = f2bf(b.x * rb); ub.y = f2bf(b.y * rb); ub.z = f2bf(b.z * rb); ub.w = f2bf(b.w * rb);
    ((ushort4*)(R1 + (size_t)row * DIM))[lane] = ua;   // zi_norm
    ((ushort4*)(R0 + (size_t)row * DIM))[lane] = ub;   // zj_norm

    if (lane == 0) pos[row] = dab * ra * rb * INV_T;
}

// Kernel 2: symmetric fused GEMM. Upper-triangular 128x128 tiles only.
// global_load_lds(16B) staging with source-side XOR swizzle (chunk c of row r
// stored at slot c^(r&7)) -> conflict-light ds_read_b128 without padding.
// Off-diagonal tiles add both row-sums and col-sums of exp(10*S).
// Last block (completion counter) computes the scalar loss.
__global__ __launch_bounds__(256, 4) void gemm_sym(
    const unsigned short* __restrict__ R0,
    const unsigned short* __restrict__ R1,
    float* __restrict__ denom,            // [2*N] fp32, counter after
    const float* __restrict__ pos,
    float* __restrict__ out)
{
    __shared__ unsigned short As[BM * BK];
    __shared__ unsigned short Bs[BM * BK];
    __shared__ int lastFlag;
    __shared__ float red[4];

    int view = blockIdx.y;
    const unsigned short* R = view ? R1 : R0;
    float* den = denom + view * N_ROWS;

    // triangular decode: blockIdx.x -> (by, bx), bx >= by
    int t = blockIdx.x;
    int by = 0;
    while (t >= NT - by) { t -= NT - by; ++by; }
    int bx = by + t;
    int rT = by * BM, cT = bx * BM;

    int tid = threadIdx.x;
    int lane = tid & 63;
    int wave = tid >> 6;
    int wy = wave >> 1, wx = wave & 1;
    int m = lane & 15, q = lane >> 4;

    floatx4 acc[4][4] = {};

    for (int kidx = 0; kidx < 4; ++kidx) {
        int k0 = kidx * BK;
        __syncthreads();
        #pragma unroll
        for (int stp = 0; stp < 4; ++stp) {
            int s = stp * 256 + tid;              // 16B slot id, lane-contiguous
            int row = s >> 3, p = s & 7;
            int cg = p ^ (row & 7);               // source chunk for this slot
            const unsigned short* ga = R + (size_t)(rT + row) * DIM + k0 + cg * 8;
            const unsigned short* gb = R + (size_t)(cT + row) * DIM + k0 + cg * 8;
            __builtin_amdgcn_global_load_lds((glb_uint*)ga, (lds_uint*)&As[s * 8], 16, 0, 0);
            __builtin_amdgcn_global_load_lds((glb_uint*)gb, (lds_uint*)&Bs[s * 8], 16, 0, 0);
        }
        __syncthreads();

        #pragma unroll
        for (int kk = 0; kk < 2; ++kk) {
            short8 af[4], bfr[4];
            #pragma unroll
            for (int tt = 0; tt < 4; ++tt) {
                int ra = wy * 64 + tt * 16 + m;
                int pa = (kk * 4 + q) ^ (ra & 7);
                af[tt] = *(const short8*)&As[(ra * 8 + pa) * 8];
                int rb = wx * 64 + tt * 16 + m;
                int pb = (kk * 4 + q) ^ (rb & 7);
                bfr[tt] = *(const short8*)&Bs[(rb * 8 + pb) * 8];
            }
            #pragma unroll
            for (int i = 0; i < 4; ++i)
                #pragma unroll
                for (int j = 0; j < 4; ++j)
                    acc[i][j] = __builtin_amdgcn_mfma_f32_16x16x32_bf16(af[i], bfr[j], acc[i][j], 0, 0, 0);
        }
    }

    // Epilogue. C/D layout: col = m, row = q*4 + r (m89/m91).
    float rs[4][4] = {};
    float cs[4] = {0.f, 0.f, 0.f, 0.f};
    #pragma unroll
    for (int i = 0; i < 4; ++i) {
        #pragma unroll
        for (int j = 0; j < 4; ++j) {
            int gcol = cT + wx * 64 + j * 16 + m;
            #pragma unroll
            for (int r = 0; r < 4; ++r) {
                int grow = rT + wy * 64 + i * 16 + q * 4 + r;
                float e = (grow == gcol) ? 0.0f : __expf(acc[i][j][r] * INV_T);
                rs[i][r] += e;
                cs[j] += e;
            }
        }
    }
    #pragma unroll
    for (int off = 1; off < 16; off <<= 1)
        #pragma unroll
        for (int i = 0; i < 4; ++i)
            #pragma unroll
            for (int r = 0; r < 4; ++r)
                rs[i][r] += __shfl_xor(rs[i][r], off);
    if (m == 0) {
        #pragma unroll
        for (int i = 0; i < 4; ++i)
            #pragma unroll
            for (int r = 0; r < 4; ++r)
                atomicAdd(&den[rT + wy * 64 + i * 16 + q * 4 + r], rs[i][r]);
    }
    if (bx != by) {   // off-diagonal: col sums feed the mirrored rows
        #pragma unroll
        for (int off = 16; off < 64; off <<= 1)
            #pragma unroll
            for (int j = 0; j < 4; ++j)
                cs[j] += __shfl_xor(cs[j], off);
        if (q == 0) {
            #pragma unroll
            for (int j = 0; j < 4; ++j)
                atomicAdd(&den[cT + wx * 64 + j * 16 + m], cs[j]);
        }
    }

    // Completion counter; last block computes loss.
    int* counter = (int*)(denom + 2 * N_ROWS);
    __threadfence();
    __syncthreads();
    if (tid == 0) lastFlag = (atomicAdd(counter, 1) == TOTAL_BLOCKS - 1);
    __syncthreads();
    if (lastFlag) {
        float s = 0.f;
        for (int r = tid; r < 2 * N_ROWS; r += 256) {
            float p = pos[r & (N_ROWS - 1)];
            float d = __hip_atomic_load(&denom[r], __ATOMIC_RELAXED, __HIP_MEMORY_SCOPE_AGENT);
            s += __logf(d + __expf(p)) - p;
        }
        #pragma unroll
        for (int off = 1; off < 64; off <<= 1) s += __shfl_xor(s, off);
        if (lane == 0) red[wave] = s;
        __syncthreads();
        if (tid == 0) out[0] = (red[0] + red[1] + red[2] + red[3]) * (1.0f / (2 * N_ROWS));
    }
}

extern "C" void kernel_launch(void* const* d_in, const int* in_sizes, int n_in,
                              void* d_out, int out_size, void* d_ws, size_t ws_size,
                              hipStream_t stream) {
    const float* z_i = (const float*)d_in[0];
    const float* z_j = (const float*)d_in[1];
    char* ws = (char*)d_ws;
    unsigned short* R0 = (unsigned short*)ws;                        // 2 MB
    unsigned short* R1 = (unsigned short*)(ws + (2u << 20));         // 2 MB
    float* pos   = (float*)(ws + (4u << 20));                        // 16 KB
    float* denom = (float*)(ws + (4u << 20) + (64u << 10));          // 32 KB + counter

    normalize_kernel<<<N_ROWS / 4, 256, 0, stream>>>(z_i, z_j, R0, R1, pos,
                                                     (unsigned int*)denom);
    dim3 grid(NTILES, 2);
    gemm_sym<<<grid, 256, 0, stream>>>(R0, R1, denom, pos, (float*)d_out);
}

// Round 3
// 101.924 us; speedup vs baseline: 1.4443x; 1.4443x over previous
//
#include <hip/hip_runtime.h>
#include <math.h>

#define N_ROWS 4096
#define DIM 256
constexpr float INV_T = 10.0f;

#define NT 32                   // 4096 / 128 tiles per view side
#define NTILES 528              // NT*(NT+1)/2 upper-triangular tiles
#define TOTAL_BLOCKS (2 * NTILES)
#define BM 128
#define BK 64

typedef __attribute__((ext_vector_type(8))) short short8;   // bf16x8 MFMA operand
typedef __attribute__((ext_vector_type(4))) float floatx4;  // fp32x4 accumulator

__device__ __forceinline__ unsigned short f2bf(float f) {
    unsigned int u = __float_as_uint(f);
    return (unsigned short)((u + 0x7FFFu + ((u >> 16) & 1u)) >> 16);  // RNE
}

// Kernel 1: one wave per row. L2-normalized bf16 rows of z_j -> R0, z_i -> R1,
// pos[r] = dot(zi_n, zj_n)*10. Also zeroes denom[8192] + completion counter.
__global__ __launch_bounds__(256) void normalize_kernel(
    const float* __restrict__ z_i, const float* __restrict__ z_j,
    unsigned short* __restrict__ R0, unsigned short* __restrict__ R1,
    float* __restrict__ pos, unsigned int* __restrict__ zero_region)
{
    int gid = blockIdx.x * 256 + threadIdx.x;
    if (gid < 2 * N_ROWS + 1) zero_region[gid] = 0u;   // denom + counter

    int wave = threadIdx.x >> 6;
    int lane = threadIdx.x & 63;
    int row = blockIdx.x * 4 + wave;

    float4 a = ((const float4*)(z_i + (size_t)row * DIM))[lane];
    float4 b = ((const float4*)(z_j + (size_t)row * DIM))[lane];

    float ssa = a.x*a.x + a.y*a.y + a.z*a.z + a.w*a.w;
    float ssb = b.x*b.x + b.y*b.y + b.z*b.z + b.w*b.w;
    float dab = a.x*b.x + a.y*b.y + a.z*b.z + a.w*b.w;
    #pragma unroll
    for (int off = 1; off < 64; off <<= 1) {
        ssa += __shfl_xor(ssa, off);
        ssb += __shfl_xor(ssb, off);
        dab += __shfl_xor(dab, off);
    }
    float ra = rsqrtf(ssa);
    float rb = rsqrtf(ssb);

    ushort4 ua, ub;
    ua.x = f2bf(a.x * ra); ua.y = f2bf(a.y * ra); ua.z = f2bf(a.z * ra); ua.w = f2bf(a.w * ra);
    ub.x = f2bf(b.x * rb); ub.y = f2bf(b.y * rb); ub.z = f2bf(b.z * rb); ub.w = f2bf(b.w * rb);
    ((ushort4*)(R1 + (size_t)row * DIM))[lane] = ua;   // zi_norm
    ((ushort4*)(R0 + (size_t)row * DIM))[lane] = ub;   // zj_norm

    if (lane == 0) pos[row] = dab * ra * rb * INV_T;
}

// Kernel 2: symmetric fused GEMM, upper-triangular 128x128 tiles.
// Staging: coalesced uint4 global loads -> XOR-swizzled ds_write_b128
// (chunk c of row r lands at slot c^(r&7)) -> conflict-free b128 reads, no pad.
// Off-diagonal tiles add row-sums AND col-sums of exp(10*S).
// Completion counter (ordered by s_waitcnt vmcnt(0), NO threadfence/L2-writeback);
// last block computes the scalar loss.
__global__ __launch_bounds__(256) void gemm_sym(
    const unsigned short* __restrict__ R0,
    const unsigned short* __restrict__ R1,
    float* __restrict__ denom,            // [2*N] fp32, counter after
    const float* __restrict__ pos,
    float* __restrict__ out)
{
    __shared__ unsigned short As[BM * BK];   // 16 KB
    __shared__ unsigned short Bs[BM * BK];   // 16 KB
    __shared__ int lastFlag;
    __shared__ float red[4];

    int view = blockIdx.y;
    const unsigned short* R = view ? R1 : R0;
    float* den = denom + view * N_ROWS;

    // triangular decode: blockIdx.x -> (by, bx), bx >= by
    int t = blockIdx.x;
    int by = 0;
    while (t >= NT - by) { t -= NT - by; ++by; }
    int bx = by + t;
    int rT = by * BM, cT = bx * BM;

    int tid = threadIdx.x;
    int lane = tid & 63;
    int wave = tid >> 6;
    int wy = wave >> 1, wx = wave & 1;
    int m = lane & 15, q = lane >> 4;

    floatx4 acc[4][4] = {};

    for (int kidx = 0; kidx < 4; ++kidx) {
        int k0 = kidx * BK;
        __syncthreads();
        #pragma unroll
        for (int it = 0; it < 4; ++it) {
            int s = it * 256 + tid;            // chunk id: 128 rows x 8 chunks
            int row = s >> 3, c = s & 7;
            uint4 va = *(const uint4*)(R + (size_t)(rT + row) * DIM + k0 + c * 8);
            uint4 vb = *(const uint4*)(R + (size_t)(cT + row) * DIM + k0 + c * 8);
            int slot = row * 8 + (c ^ (row & 7));
            *(uint4*)&As[slot * 8] = va;
            *(uint4*)&Bs[slot * 8] = vb;
        }
        __syncthreads();

        #pragma unroll
        for (int kk = 0; kk < 2; ++kk) {
            short8 af[4], bfr[4];
            #pragma unroll
            for (int tt = 0; tt < 4; ++tt) {
                int ra = wy * 64 + tt * 16 + m;
                af[tt] = *(const short8*)&As[(ra * 8 + ((kk * 4 + q) ^ (ra & 7))) * 8];
                int rb = wx * 64 + tt * 16 + m;
                bfr[tt] = *(const short8*)&Bs[(rb * 8 + ((kk * 4 + q) ^ (rb & 7))) * 8];
            }
            #pragma unroll
            for (int i = 0; i < 4; ++i)
                #pragma unroll
                for (int j = 0; j < 4; ++j)
                    acc[i][j] = __builtin_amdgcn_mfma_f32_16x16x32_bf16(af[i], bfr[j], acc[i][j], 0, 0, 0);
        }
    }

    // Epilogue. C/D layout: col = m, row = q*4 + r (m89/m91).
    float rs[4][4] = {};
    float cs[4] = {0.f, 0.f, 0.f, 0.f};
    #pragma unroll
    for (int i = 0; i < 4; ++i) {
        #pragma unroll
        for (int j = 0; j < 4; ++j) {
            int gcol = cT + wx * 64 + j * 16 + m;
            #pragma unroll
            for (int r = 0; r < 4; ++r) {
                int grow = rT + wy * 64 + i * 16 + q * 4 + r;
                float e = (grow == gcol) ? 0.0f : __expf(acc[i][j][r] * INV_T);
                rs[i][r] += e;
                cs[j] += e;
            }
        }
    }
    #pragma unroll
    for (int off = 1; off < 16; off <<= 1)
        #pragma unroll
        for (int i = 0; i < 4; ++i)
            #pragma unroll
            for (int r = 0; r < 4; ++r)
                rs[i][r] += __shfl_xor(rs[i][r], off);
    if (m == 0) {
        #pragma unroll
        for (int i = 0; i < 4; ++i)
            #pragma unroll
            for (int r = 0; r < 4; ++r)
                atomicAdd(&den[rT + wy * 64 + i * 16 + q * 4 + r], rs[i][r]);
    }
    if (bx != by) {   // off-diagonal: col sums feed the mirrored rows
        #pragma unroll
        for (int off = 16; off < 64; off <<= 1)
            #pragma unroll
            for (int j = 0; j < 4; ++j)
                cs[j] += __shfl_xor(cs[j], off);
        if (q == 0) {
            #pragma unroll
            for (int j = 0; j < 4; ++j)
                atomicAdd(&den[cT + wx * 64 + j * 16 + m], cs[j]);
        }
    }

    // Order prior device-scope atomics (vmcnt-tracked, acked at coherence point)
    // before the completion-counter RMW. NO __threadfence(): that emits
    // buffer_wbl2 (per-XCD L2 writeback scan) per block -- the round-2 91us bug.
    asm volatile("s_waitcnt vmcnt(0)" ::: "memory");
    __syncthreads();
    int* counter = (int*)(denom + 2 * N_ROWS);
    if (tid == 0) lastFlag = (atomicAdd(counter, 1) == TOTAL_BLOCKS - 1);
    __syncthreads();
    if (lastFlag) {
        float s = 0.f;
        for (int r = tid; r < 2 * N_ROWS; r += 256) {
            float p = pos[r & (N_ROWS - 1)];
            float d = __hip_atomic_load(&denom[r], __ATOMIC_RELAXED, __HIP_MEMORY_SCOPE_AGENT);
            s += __logf(d + __expf(p)) - p;
        }
        #pragma unroll
        for (int off = 1; off < 64; off <<= 1) s += __shfl_xor(s, off);
        if (lane == 0) red[wave] = s;
        __syncthreads();
        if (tid == 0) out[0] = (red[0] + red[1] + red[2] + red[3]) * (1.0f / (2 * N_ROWS));
    }
}

extern "C" void kernel_launch(void* const* d_in, const int* in_sizes, int n_in,
                              void* d_out, int out_size, void* d_ws, size_t ws_size,
                              hipStream_t stream) {
    const float* z_i = (const float*)d_in[0];
    const float* z_j = (const float*)d_in[1];
    char* ws = (char*)d_ws;
    unsigned short* R0 = (unsigned short*)ws;                        // 2 MB
    unsigned short* R1 = (unsigned short*)(ws + (2u << 20));         // 2 MB
    float* pos   = (float*)(ws + (4u << 20));                        // 16 KB
    float* denom = (float*)(ws + (4u << 20) + (64u << 10));          // 32 KB + counter

    normalize_kernel<<<N_ROWS / 4, 256, 0, stream>>>(z_i, z_j, R0, R1, pos,
                                                     (unsigned int*)denom);
    dim3 grid(NTILES, 2);
    gemm_sym<<<grid, 256, 0, stream>>>(R0, R1, denom, pos, (float*)d_out);
}